// Round 5
// baseline (1046.802 us; speedup 1.0000x reference)
//
#include <hip/hip_runtime.h>
#include <hip/hip_bf16.h>

// ---------------------------------------------------------------------------
// SPIntraAttModuleV5:  B=4, N=4096, C=256, S=256, K=32, NSAMPLES=30, EPS=1e-8
// Round 5: exp-domain sampling. argmax(logit+gumbel) == argmin((-ln u)/w),
// w = a+1e-8. Screen = threefry + ONE v_log + mul + top-2 min tracking.
// Certified unique -> done; else rare full bit-exact reference rescan.
// Labels bit-identical to rounds 1-4. Attn/topk/binning unchanged.
// ---------------------------------------------------------------------------

#define BB 4
#define NN 4096
#define CC 256
#define SS 256
#define KKK 32
#define NSAMP 30
#define NBIN (BB*SS)            // 1024
#define TOTQ (NSAMP*BB*NN)      // 491520

typedef _Float16 half8 __attribute__((ext_vector_type(8)));
typedef _Float16 half4v __attribute__((ext_vector_type(4)));
typedef float f32x4 __attribute__((ext_vector_type(4)));

struct Keys30 { unsigned k0[NSAMP]; unsigned k1[NSAMP]; };

__host__ __device__ __forceinline__ void threefry2x32(unsigned k0, unsigned k1,
    unsigned x0, unsigned x1, unsigned& o0, unsigned& o1) {
  unsigned ks2 = k0 ^ k1 ^ 0x1BD11BDAu;
#define TFROT(r) { x0 += x1; x1 = __builtin_rotateleft32(x1, (r)); x1 ^= x0; }
  x0 += k0; x1 += k1;
  TFROT(13) TFROT(15) TFROT(26) TFROT(6)
  x0 += k1;  x1 += ks2 + 1u;
  TFROT(17) TFROT(29) TFROT(16) TFROT(24)
  x0 += ks2; x1 += k0 + 2u;
  TFROT(13) TFROT(15) TFROT(26) TFROT(6)
  x0 += k0;  x1 += k1 + 3u;
  TFROT(17) TFROT(29) TFROT(16) TFROT(24)
  x0 += k1;  x1 += ks2 + 4u;
  TFROT(13) TFROT(15) TFROT(26) TFROT(6)
  x0 += ks2; x1 += k0 + 5u;
#undef TFROT
  o0 = x0; o1 = x1;
}

__device__ __forceinline__ float uniform_from_bits(unsigned bits) {
  float u = __uint_as_float((bits >> 9) | 0x3f800000u) - 1.0f;
  return fmaxf(u, 1.17549435e-38f);
}

// exact (reference-matching) gumbel: ocml logf path, as rounds 1-4
__device__ __forceinline__ float gumbel_exact(unsigned bits) {
  float u = uniform_from_bits(bits);
  return -logf(-logf(u));
}

// ---------------------------------------------------------------------------
// ninvw = -1/(am + EPS)  (fp32 precise divide; feeds the sampling screen)
// ---------------------------------------------------------------------------
__global__ __launch_bounds__(256) void invw_kernel(const float* __restrict__ am,
                                                   float* __restrict__ nw) {
  int i = (blockIdx.x * 256 + threadIdx.x) << 2;
  float4 v = *(const float4*)&am[i];
  float4 o;
  o.x = -1.0f / (v.x + 1e-8f); o.y = -1.0f / (v.y + 1e-8f);
  o.z = -1.0f / (v.z + 1e-8f); o.w = -1.0f / (v.w + 1e-8f);
  *(float4*)&nw[i] = o;
}

// ---------------------------------------------------------------------------
// top-32 per amatrix row; tie -> lower index (matches lax.top_k)
// ---------------------------------------------------------------------------
__global__ __launch_bounds__(256) void topk_kernel(const float* __restrict__ am,
                                                   int* __restrict__ indices,
                                                   float* __restrict__ logw) {
  __shared__ float vals[NN];
  __shared__ float wv[4];
  __shared__ int   wi[4];
  const int row = blockIdx.x;            // b*S + s
  const int tid = threadIdx.x;
  const float* src = am + (size_t)row * NN;
  for (int i = tid; i < NN; i += 256) vals[i] = src[i];
  __syncthreads();
  for (int k = 0; k < KKK; ++k) {
    float bv = -INFINITY; int bi = -1;
    #pragma unroll
    for (int j = 0; j < NN / 256; ++j) {
      int idx = tid + j * 256;
      float v = vals[idx];
      if (v > bv) { bv = v; bi = idx; }
    }
    #pragma unroll
    for (int off = 32; off; off >>= 1) {
      float ov = __shfl_down(bv, off);
      int   oi = __shfl_down(bi, off);
      if (ov > bv || (ov == bv && oi < bi)) { bv = ov; bi = oi; }
    }
    if ((tid & 63) == 0) { wv[tid >> 6] = bv; wi[tid >> 6] = bi; }
    __syncthreads();
    if (tid == 0) {
      bv = wv[0]; bi = wi[0];
      for (int w = 1; w < 4; ++w)
        if (wv[w] > bv || (wv[w] == bv && wi[w] < bi)) { bv = wv[w]; bi = wi[w]; }
      indices[row * KKK + k] = bi;
      logw[row * KKK + k] = logf(bv + 1e-8f);
      vals[bi] = -INFINITY;
    }
    __syncthreads();
  }
}

// ---------------------------------------------------------------------------
// Exp-domain Gumbel argmax:  label = argmin_s (-log2(u_s)) * (-1/w_s)
// (positive ratio; log2 vs ln and the sign fold are constant monotone maps).
// Top-2 tracking certifies the argmin; uncertified lanes (P ~ 1e-4) run a
// full bit-exact reference replication. Labels identical to naive scan.
// ---------------------------------------------------------------------------
__global__ __launch_bounds__(256) void sample_top2_kernel(
    const float* __restrict__ ninvw, const float* __restrict__ am,
    unsigned char* __restrict__ labels, Keys30 keys) {
  const int t0 = blockIdx.x * 256 + threadIdx.x;   // t0 < NSAMP*BB*NN
  const int n = t0 & (NN - 1);
  const int b = (t0 >> 12) & 3;
  const int samp = t0 >> 14;
  const unsigned k0 = keys.k0[samp], k1 = keys.k1[samp];
  const unsigned jbase = ((unsigned)((b << 12) + n)) << 8;   // (b*N+n)*S
  const float* wcol = ninvw + ((size_t)(b << 8)) * NN + n;   // wcol[s*NN]

  float r1 = INFINITY, r2 = INFINITY;  // smallest / second-smallest ratio
  int   i1 = 0;
  #pragma unroll 8
  for (int s = 0; s < SS; ++s) {
    unsigned o0, o1;
    threefry2x32(k0, k1, 0u, jbase + (unsigned)s, o0, o1);
    float u = uniform_from_bits(o0 ^ o1);
    // r = (-log2 u) / w  ==  v_log(u) * (-1/w)   (both factors negative)
    float r = __builtin_amdgcn_logf(u) * wcol[(size_t)s * NN];
    bool better = r < r1;
    r2 = better ? r1 : fminf(r2, r);
    r1 = better ? r  : r1;
    i1 = better ? s  : i1;
  }
  // certification: top-2 log-domain gap must exceed 1e-4 (>> total approx +
  // reference-fp error). Otherwise replicate the reference scan bit-exactly.
  bool uncert = !(r2 > r1 * 1.0001f);
  if (__ballot(uncert)) {
    if (uncert) {
      const float* acol = am + ((size_t)(b << 8)) * NN + n;
      float best = -INFINITY; int bi = 0;
      for (int s = 0; s < SS; ++s) {
        unsigned o0, o1;
        threefry2x32(k0, k1, 0u, jbase + (unsigned)s, o0, o1);
        float tot = gumbel_exact(o0 ^ o1) + logf(acol[(size_t)s * NN] + 1e-8f);
        if (tot > best) { best = tot; bi = s; }
      }
      i1 = bi;
    }
  }
  labels[((samp << 2) + b) * NN + n] = (unsigned char)i1;
}

// ---------------------------------------------------------------------------
// binning: histogram -> exclusive scan -> scatter pixel ids into bins
// ---------------------------------------------------------------------------
__global__ __launch_bounds__(256) void hist_kernel(const unsigned char* __restrict__ lbl,
                                                   int* __restrict__ hist) {
  __shared__ int h[NBIN];
  for (int i = threadIdx.x; i < NBIN; i += 256) h[i] = 0;
  __syncthreads();
  for (int e = blockIdx.x * 256 + threadIdx.x; e < TOTQ; e += gridDim.x * 256) {
    int bgrp = (e >> 12) & 3;
    atomicAdd(&h[(bgrp << 8) + lbl[e]], 1);
  }
  __syncthreads();
  for (int i = threadIdx.x; i < NBIN; i += 256) if (h[i]) atomicAdd(&hist[i], h[i]);
}

__global__ __launch_bounds__(1024) void scan_kernel(const int* __restrict__ hist,
                                                    int* __restrict__ binstart,
                                                    int* __restrict__ cursor) {
  __shared__ int a[NBIN];
  const int tid = threadIdx.x;
  const int h = hist[tid];
  a[tid] = h;
  __syncthreads();
  for (int off = 1; off < NBIN; off <<= 1) {
    int v = (tid >= off) ? a[tid - off] : 0;
    __syncthreads();
    a[tid] += v;
    __syncthreads();
  }
  int excl = a[tid] - h;
  binstart[tid] = excl;
  cursor[tid]   = excl;
}

__global__ __launch_bounds__(256) void scatter_kernel(const unsigned char* __restrict__ lbl,
                                                      int* __restrict__ cursor,
                                                      int* __restrict__ qlist) {
  for (int e = blockIdx.x * 256 + threadIdx.x; e < TOTQ; e += gridDim.x * 256) {
    int bgrp = (e >> 12) & 3;
    int bin = (bgrp << 8) + lbl[e];
    int slot = atomicAdd(&cursor[bin], 1);
    qlist[slot] = e & (NN - 1);          // pixel id n (b implicit in bin)
  }
}

// ---------------------------------------------------------------------------
// Binned MFMA attention (unchanged from round 2).
// ---------------------------------------------------------------------------
__global__ __launch_bounds__(256, 2) void attn_mfma_kernel(
    const float* __restrict__ x, const int* __restrict__ indices,
    const float* __restrict__ logw, const int* __restrict__ qlist,
    const int* __restrict__ binstart, const int* __restrict__ hist,
    float* __restrict__ out) {
  __shared__ _Float16 Qlds[64 * 256];   // swizzled: elem ^ ((row&7)<<3)
  __shared__ _Float16 Klds[32 * 256];   // swizzled
  __shared__ _Float16 KT[256 * 40];     // KT[ch][key], stride 40 halves
  __shared__ _Float16 Plds[4 * 16 * 32];
  __shared__ int   kidx_s[KKK];
  __shared__ float kbias_s[KKK];

  const int tid = threadIdx.x;
  const int b = blockIdx.x & 3;
  const int s = blockIdx.x >> 2;
  const int bin = (b << 8) + s;
  const int base = binstart[bin];
  const int cnt  = hist[bin];

  if (tid < KKK) {
    int r = bin * KKK + tid;
    kidx_s[tid]  = indices[r];
    kbias_s[tid] = logw[r];
  }
  __syncthreads();

  const int w = tid >> 6, lane = tid & 63;
  const int qr = lane & 15, kg = lane >> 4;

  // ---- stage keys: Klds (swizzled row-major) + KT (transposed) ----
  {
    const int c4 = (lane) << 2;
    #pragma unroll
    for (int p = 0; p < 8; ++p) {
      int r = (p << 2) + w;
      const float4 v = *(const float4*)&x[((size_t)((b << 12) + kidx_s[r]) << 8) + c4];
      half4v h;
      h[0] = (_Float16)v.x; h[1] = (_Float16)v.y;
      h[2] = (_Float16)v.z; h[3] = (_Float16)v.w;
      *(half4v*)&Klds[(r << 8) + (c4 ^ ((r & 7) << 3))] = h;
      KT[(c4 + 0) * 40 + r] = h[0];
      KT[(c4 + 1) * 40 + r] = h[1];
      KT[(c4 + 2) * 40 + r] = h[2];
      KT[(c4 + 3) * 40 + r] = h[3];
    }
  }

  const int nchunk = (cnt + 63) >> 6;
  for (int chk = 0; chk < nchunk; ++chk) {
    const int rmax = min(64, cnt - (chk << 6));
    __syncthreads();
    // ---- stage 64 query rows (fp32 -> fp16, swizzled) ----
    {
      const int c4 = lane << 2;
      #pragma unroll
      for (int p = 0; p < 16; ++p) {
        int r = (p << 2) + w;
        int rr = min(r, rmax - 1);
        int n = qlist[base + (chk << 6) + rr];
        const float4 v = *(const float4*)&x[((size_t)((b << 12) + n) << 8) + c4];
        half4v h;
        h[0] = (_Float16)v.x; h[1] = (_Float16)v.y;
        h[2] = (_Float16)v.z; h[3] = (_Float16)v.w;
        *(half4v*)&Qlds[(r << 8) + (c4 ^ ((r & 7) << 3))] = h;
      }
    }
    __syncthreads();

    // ---- S = Q K^T / 16 + bias ----
    f32x4 acc0 = {0.f, 0.f, 0.f, 0.f}, acc1 = {0.f, 0.f, 0.f, 0.f};
    {
      const int arow = (w << 4) + qr;
      const _Float16* Arow = &Qlds[arow << 8];
      const int asz = (arow & 7) << 3;
      const _Float16* B0 = &Klds[qr << 8];
      const _Float16* B1 = &Klds[(16 + qr) << 8];
      const int bsz = (qr & 7) << 3;
      #pragma unroll
      for (int kk = 0; kk < 8; ++kk) {
        const int off = (kk << 5) + (kg << 3);
        half8 a  = *(const half8*)&Arow[off ^ asz];
        half8 b0 = *(const half8*)&B0[off ^ bsz];
        half8 b1 = *(const half8*)&B1[off ^ bsz];
        acc0 = __builtin_amdgcn_mfma_f32_16x16x32_f16(a, b0, acc0, 0, 0, 0);
        acc1 = __builtin_amdgcn_mfma_f32_16x16x32_f16(a, b1, acc1, 0, 0, 0);
      }
    }
    // ---- softmax over 32 keys per query row; P -> LDS (fp16) ----
    {
      const float b0v = kbias_s[qr], b1v = kbias_s[16 + qr];
      #pragma unroll
      for (int r = 0; r < 4; ++r) {
        float s0 = acc0[r] * 0.0625f + b0v;
        float s1 = acc1[r] * 0.0625f + b1v;
        float m = fmaxf(s0, s1);
        #pragma unroll
        for (int o = 1; o < 16; o <<= 1) m = fmaxf(m, __shfl_xor(m, o));
        float e0 = __expf(s0 - m), e1 = __expf(s1 - m);
        float sm = e0 + e1;
        #pragma unroll
        for (int o = 1; o < 16; o <<= 1) sm += __shfl_xor(sm, o);
        float inv = 1.0f / sm;
        int prow = (kg << 2) + r;
        _Float16* P = &Plds[(w << 9) + (prow << 5)];
        P[qr]      = (_Float16)(e0 * inv);
        P[16 + qr] = (_Float16)(e1 * inv);
      }
    }
    __builtin_amdgcn_wave_barrier();
    // ---- O = P K ; atomic accumulate ----
    {
      half8 a2 = *(const half8*)&Plds[(w << 9) + (qr << 5) + (kg << 3)];
      int nr[4];
      #pragma unroll
      for (int r = 0; r < 4; ++r) {
        int grow = (w << 4) + (kg << 2) + r;
        nr[r] = (grow < rmax) ? qlist[base + (chk << 6) + grow] : -1;
      }
      #pragma unroll
      for (int t = 0; t < 16; ++t) {
        half8 bb = *(const half8*)&KT[((t << 4) + qr) * 40 + (kg << 3)];
        f32x4 zero = {0.f, 0.f, 0.f, 0.f};
        f32x4 o = __builtin_amdgcn_mfma_f32_16x16x32_f16(a2, bb, zero, 0, 0, 0);
        #pragma unroll
        for (int r = 0; r < 4; ++r) {
          if (nr[r] >= 0)
            atomicAdd(&out[((size_t)((b << 12) + nr[r]) << 8) + (t << 4) + qr],
                      o[r] * (1.0f / 30.0f));
        }
      }
    }
  }
}

// ---------------------------------------------------------------------------
// workspace layout (bytes)
#define OFF_IDX   0                      // 128K
#define OFF_LOGW  131072                 // 128K
#define OFF_LBL   262144                 // 480K
#define OFF_NW    786432                 // 16 MB (ninvw table)
#define OFF_HIST  17563648               // 4K
#define OFF_BST   17567744               // 4K
#define OFF_CUR   17571840               // 4K
#define OFF_QL    17575936               // 1.875 MB (end ~19.5 MB)

extern "C" void kernel_launch(void* const* d_in, const int* in_sizes, int n_in,
                              void* d_out, int out_size, void* d_ws, size_t ws_size,
                              hipStream_t stream) {
  const float* x  = (const float*)d_in[0];
  const float* am = (const float*)d_in[1];
  float* out = (float*)d_out;

  char* ws = (char*)d_ws;
  int*   indices = (int*)(ws + OFF_IDX);
  float* logw    = (float*)(ws + OFF_LOGW);
  unsigned char* labels = (unsigned char*)(ws + OFF_LBL);
  float* ninvw   = (float*)(ws + OFF_NW);
  int*   hist    = (int*)(ws + OFF_HIST);
  int*   binstart= (int*)(ws + OFF_BST);
  int*   cursor  = (int*)(ws + OFF_CUR);
  int*   qlist   = (int*)(ws + OFF_QL);

  Keys30 keys;
  for (int s = 0; s < NSAMP; ++s) {
    unsigned o0, o1;
    threefry2x32(0u, 1u, 0u, (unsigned)s, o0, o1);
    keys.k0[s] = o0; keys.k1[s] = o1;
  }

  hipMemsetAsync(d_out, 0, (size_t)out_size * 4, stream);
  hipMemsetAsync(hist, 0, NBIN * 4, stream);

  invw_kernel<<<(BB * SS * NN) / (256 * 4), 256, 0, stream>>>(am, ninvw);
  topk_kernel<<<BB * SS, 256, 0, stream>>>(am, indices, logw);
  sample_top2_kernel<<<TOTQ / 256, 256, 0, stream>>>(ninvw, am, labels, keys);
  hist_kernel<<<240, 256, 0, stream>>>(labels, hist);
  scan_kernel<<<1, 1024, 0, stream>>>(hist, binstart, cursor);
  scatter_kernel<<<240, 256, 0, stream>>>(labels, cursor, qlist);
  attn_mfma_kernel<<<NBIN, 256, 0, stream>>>(x, indices, logw, qlist, binstart,
                                             hist, out);
}

// Round 6
// 1017.025 us; speedup vs baseline: 1.0293x; 1.0293x over previous
//
#include <hip/hip_runtime.h>
#include <hip/hip_bf16.h>

// ---------------------------------------------------------------------------
// SPIntraAttModuleV5:  B=4, N=4096, C=256, S=256, K=32, NSAMPLES=30, EPS=1e-8
// Round 6: exp-domain sampling with ILP-2 (two independent 128-class chains)
// and a CHEAP windowed rescue (no more 256-class ocml rescan tail).
// Labels bit-identical to rounds 1-5. Attn/topk/binning unchanged.
// ---------------------------------------------------------------------------

#define BB 4
#define NN 4096
#define CC 256
#define SS 256
#define KKK 32
#define NSAMP 30
#define NBIN (BB*SS)            // 1024
#define TOTQ (NSAMP*BB*NN)      // 491520

typedef _Float16 half8 __attribute__((ext_vector_type(8)));
typedef _Float16 half4v __attribute__((ext_vector_type(4)));
typedef float f32x4 __attribute__((ext_vector_type(4)));

struct Keys30 { unsigned k0[NSAMP]; unsigned k1[NSAMP]; };

__host__ __device__ __forceinline__ void threefry2x32(unsigned k0, unsigned k1,
    unsigned x0, unsigned x1, unsigned& o0, unsigned& o1) {
  unsigned ks2 = k0 ^ k1 ^ 0x1BD11BDAu;
#define TFROT(r) { x0 += x1; x1 = __builtin_rotateleft32(x1, (r)); x1 ^= x0; }
  x0 += k0; x1 += k1;
  TFROT(13) TFROT(15) TFROT(26) TFROT(6)
  x0 += k1;  x1 += ks2 + 1u;
  TFROT(17) TFROT(29) TFROT(16) TFROT(24)
  x0 += ks2; x1 += k0 + 2u;
  TFROT(13) TFROT(15) TFROT(26) TFROT(6)
  x0 += k0;  x1 += k1 + 3u;
  TFROT(17) TFROT(29) TFROT(16) TFROT(24)
  x0 += k1;  x1 += ks2 + 4u;
  TFROT(13) TFROT(15) TFROT(26) TFROT(6)
  x0 += ks2; x1 += k0 + 5u;
#undef TFROT
  o0 = x0; o1 = x1;
}

__device__ __forceinline__ float uniform_from_bits(unsigned bits) {
  float u = __uint_as_float((bits >> 9) | 0x3f800000u) - 1.0f;
  return fmaxf(u, 1.17549435e-38f);
}

// exact (reference-matching) gumbel: ocml logf path, as rounds 1-5
__device__ __forceinline__ float gumbel_exact(unsigned bits) {
  float u = uniform_from_bits(bits);
  return -logf(-logf(u));
}

// ---------------------------------------------------------------------------
// ninvw = -1/(am + EPS)
// ---------------------------------------------------------------------------
__global__ __launch_bounds__(256) void invw_kernel(const float* __restrict__ am,
                                                   float* __restrict__ nw) {
  int i = (blockIdx.x * 256 + threadIdx.x) << 2;
  float4 v = *(const float4*)&am[i];
  float4 o;
  o.x = -1.0f / (v.x + 1e-8f); o.y = -1.0f / (v.y + 1e-8f);
  o.z = -1.0f / (v.z + 1e-8f); o.w = -1.0f / (v.w + 1e-8f);
  *(float4*)&nw[i] = o;
}

// ---------------------------------------------------------------------------
// top-32 per amatrix row; tie -> lower index (matches lax.top_k)
// ---------------------------------------------------------------------------
__global__ __launch_bounds__(256) void topk_kernel(const float* __restrict__ am,
                                                   int* __restrict__ indices,
                                                   float* __restrict__ logw) {
  __shared__ float vals[NN];
  __shared__ float wv[4];
  __shared__ int   wi[4];
  const int row = blockIdx.x;            // b*S + s
  const int tid = threadIdx.x;
  const float* src = am + (size_t)row * NN;
  for (int i = tid; i < NN; i += 256) vals[i] = src[i];
  __syncthreads();
  for (int k = 0; k < KKK; ++k) {
    float bv = -INFINITY; int bi = -1;
    #pragma unroll
    for (int j = 0; j < NN / 256; ++j) {
      int idx = tid + j * 256;
      float v = vals[idx];
      if (v > bv) { bv = v; bi = idx; }
    }
    #pragma unroll
    for (int off = 32; off; off >>= 1) {
      float ov = __shfl_down(bv, off);
      int   oi = __shfl_down(bi, off);
      if (ov > bv || (ov == bv && oi < bi)) { bv = ov; bi = oi; }
    }
    if ((tid & 63) == 0) { wv[tid >> 6] = bv; wi[tid >> 6] = bi; }
    __syncthreads();
    if (tid == 0) {
      bv = wv[0]; bi = wi[0];
      for (int w = 1; w < 4; ++w)
        if (wv[w] > bv || (wv[w] == bv && wi[w] < bi)) { bv = wv[w]; bi = wi[w]; }
      indices[row * KKK + k] = bi;
      logw[row * KKK + k] = logf(bv + 1e-8f);
      vals[bi] = -INFINITY;
    }
    __syncthreads();
  }
}

// ---------------------------------------------------------------------------
// Exp-domain Gumbel argmax, ILP-2:
//   label = argmin_s (-log2 u_s) * (-1/w_s)
// Two independent 128-class chains -> merged top-2. Certified (rel gap >1e-4)
// -> done. Else: cheap windowed rescue -- rescan with the SAME cheap screen,
// exact-eval (reference ocml path, ascending s, strict >) only classes with
// r <= r1*1.0002 (~2 classes). Labels bit-identical to the naive scan.
// ---------------------------------------------------------------------------
__global__ __launch_bounds__(64) void sample_ilp2_kernel(
    const float* __restrict__ ninvw, const float* __restrict__ am,
    unsigned char* __restrict__ labels, Keys30 keys) {
  const int t0 = blockIdx.x * 64 + threadIdx.x;   // t0 < NSAMP*BB*NN
  const int n = t0 & (NN - 1);
  const int b = (t0 >> 12) & 3;
  const int samp = t0 >> 14;
  const unsigned k0 = keys.k0[samp], k1 = keys.k1[samp];
  const unsigned jbase = ((unsigned)((b << 12) + n)) << 8;   // (b*N+n)*S
  const float* wcol = ninvw + ((size_t)(b << 8)) * NN + n;   // wcol[s*NN]

  float r1a = INFINITY, r2a = INFINITY; int i1a = 0;
  float r1b = INFINITY, r2b = INFINITY; int i1b = 128;
  const float* pa = wcol;
  const float* pb = wcol + (size_t)128 * NN;
  #pragma unroll 4
  for (int s = 0; s < 128; ++s) {
    unsigned o0, o1, q0, q1;
    threefry2x32(k0, k1, 0u, jbase + (unsigned)s, o0, o1);
    threefry2x32(k0, k1, 0u, jbase + (unsigned)(s + 128), q0, q1);
    float ua = uniform_from_bits(o0 ^ o1);
    float ub = uniform_from_bits(q0 ^ q1);
    float ra = __builtin_amdgcn_logf(ua) * (*pa);
    float rb = __builtin_amdgcn_logf(ub) * (*pb);
    pa += NN; pb += NN;
    bool ba = ra < r1a;
    r2a = fminf(r2a, fmaxf(ra, r1a));
    r1a = fminf(r1a, ra);
    i1a = ba ? s : i1a;
    bool bb = rb < r1b;
    r2b = fminf(r2b, fmaxf(rb, r1b));
    r1b = fminf(r1b, rb);
    i1b = bb ? (s + 128) : i1b;
  }
  // merge top-2 of the two chains (tie -> chain a = lower index)
  bool bwin = r1b < r1a;
  float r1 = bwin ? r1b : r1a;
  int   i1 = bwin ? i1b : i1a;
  float r2 = fminf(fmaxf(r1a, r1b), fminf(r2a, r2b));

  bool uncert = !(r2 > r1 * 1.0001f);
  if (__ballot(uncert)) {
    if (uncert) {
      const float* acol = am + ((size_t)(b << 8)) * NN + n;
      const float lim = r1 * 1.0002f;
      float best = -INFINITY; int bi = 0;
      for (int s = 0; s < SS; ++s) {
        unsigned o0, o1;
        threefry2x32(k0, k1, 0u, jbase + (unsigned)s, o0, o1);
        float u = uniform_from_bits(o0 ^ o1);
        float r = __builtin_amdgcn_logf(u) * wcol[(size_t)s * NN];
        if (r <= lim) {   // ~2 classes: exact reference eval, ascending order
          float tot = gumbel_exact(o0 ^ o1) + logf(acol[(size_t)s * NN] + 1e-8f);
          if (tot > best) { best = tot; bi = s; }
        }
      }
      i1 = bi;
    }
  }
  labels[((samp << 2) + b) * NN + n] = (unsigned char)i1;
}

// ---------------------------------------------------------------------------
// binning: histogram -> exclusive scan -> scatter pixel ids into bins
// ---------------------------------------------------------------------------
__global__ __launch_bounds__(256) void hist_kernel(const unsigned char* __restrict__ lbl,
                                                   int* __restrict__ hist) {
  __shared__ int h[NBIN];
  for (int i = threadIdx.x; i < NBIN; i += 256) h[i] = 0;
  __syncthreads();
  for (int e = blockIdx.x * 256 + threadIdx.x; e < TOTQ; e += gridDim.x * 256) {
    int bgrp = (e >> 12) & 3;
    atomicAdd(&h[(bgrp << 8) + lbl[e]], 1);
  }
  __syncthreads();
  for (int i = threadIdx.x; i < NBIN; i += 256) if (h[i]) atomicAdd(&hist[i], h[i]);
}

__global__ __launch_bounds__(1024) void scan_kernel(const int* __restrict__ hist,
                                                    int* __restrict__ binstart,
                                                    int* __restrict__ cursor) {
  __shared__ int a[NBIN];
  const int tid = threadIdx.x;
  const int h = hist[tid];
  a[tid] = h;
  __syncthreads();
  for (int off = 1; off < NBIN; off <<= 1) {
    int v = (tid >= off) ? a[tid - off] : 0;
    __syncthreads();
    a[tid] += v;
    __syncthreads();
  }
  int excl = a[tid] - h;
  binstart[tid] = excl;
  cursor[tid]   = excl;
}

__global__ __launch_bounds__(256) void scatter_kernel(const unsigned char* __restrict__ lbl,
                                                      int* __restrict__ cursor,
                                                      int* __restrict__ qlist) {
  for (int e = blockIdx.x * 256 + threadIdx.x; e < TOTQ; e += gridDim.x * 256) {
    int bgrp = (e >> 12) & 3;
    int bin = (bgrp << 8) + lbl[e];
    int slot = atomicAdd(&cursor[bin], 1);
    qlist[slot] = e & (NN - 1);          // pixel id n (b implicit in bin)
  }
}

// ---------------------------------------------------------------------------
// Binned MFMA attention (unchanged from round 2).
// ---------------------------------------------------------------------------
__global__ __launch_bounds__(256, 2) void attn_mfma_kernel(
    const float* __restrict__ x, const int* __restrict__ indices,
    const float* __restrict__ logw, const int* __restrict__ qlist,
    const int* __restrict__ binstart, const int* __restrict__ hist,
    float* __restrict__ out) {
  __shared__ _Float16 Qlds[64 * 256];   // swizzled: elem ^ ((row&7)<<3)
  __shared__ _Float16 Klds[32 * 256];   // swizzled
  __shared__ _Float16 KT[256 * 40];     // KT[ch][key], stride 40 halves
  __shared__ _Float16 Plds[4 * 16 * 32];
  __shared__ int   kidx_s[KKK];
  __shared__ float kbias_s[KKK];

  const int tid = threadIdx.x;
  const int b = blockIdx.x & 3;
  const int s = blockIdx.x >> 2;
  const int bin = (b << 8) + s;
  const int base = binstart[bin];
  const int cnt  = hist[bin];

  if (tid < KKK) {
    int r = bin * KKK + tid;
    kidx_s[tid]  = indices[r];
    kbias_s[tid] = logw[r];
  }
  __syncthreads();

  const int w = tid >> 6, lane = tid & 63;
  const int qr = lane & 15, kg = lane >> 4;

  // ---- stage keys: Klds (swizzled row-major) + KT (transposed) ----
  {
    const int c4 = (lane) << 2;
    #pragma unroll
    for (int p = 0; p < 8; ++p) {
      int r = (p << 2) + w;
      const float4 v = *(const float4*)&x[((size_t)((b << 12) + kidx_s[r]) << 8) + c4];
      half4v h;
      h[0] = (_Float16)v.x; h[1] = (_Float16)v.y;
      h[2] = (_Float16)v.z; h[3] = (_Float16)v.w;
      *(half4v*)&Klds[(r << 8) + (c4 ^ ((r & 7) << 3))] = h;
      KT[(c4 + 0) * 40 + r] = h[0];
      KT[(c4 + 1) * 40 + r] = h[1];
      KT[(c4 + 2) * 40 + r] = h[2];
      KT[(c4 + 3) * 40 + r] = h[3];
    }
  }

  const int nchunk = (cnt + 63) >> 6;
  for (int chk = 0; chk < nchunk; ++chk) {
    const int rmax = min(64, cnt - (chk << 6));
    __syncthreads();
    // ---- stage 64 query rows (fp32 -> fp16, swizzled) ----
    {
      const int c4 = lane << 2;
      #pragma unroll
      for (int p = 0; p < 16; ++p) {
        int r = (p << 2) + w;
        int rr = min(r, rmax - 1);
        int n = qlist[base + (chk << 6) + rr];
        const float4 v = *(const float4*)&x[((size_t)((b << 12) + n) << 8) + c4];
        half4v h;
        h[0] = (_Float16)v.x; h[1] = (_Float16)v.y;
        h[2] = (_Float16)v.z; h[3] = (_Float16)v.w;
        *(half4v*)&Qlds[(r << 8) + (c4 ^ ((r & 7) << 3))] = h;
      }
    }
    __syncthreads();

    // ---- S = Q K^T / 16 + bias ----
    f32x4 acc0 = {0.f, 0.f, 0.f, 0.f}, acc1 = {0.f, 0.f, 0.f, 0.f};
    {
      const int arow = (w << 4) + qr;
      const _Float16* Arow = &Qlds[arow << 8];
      const int asz = (arow & 7) << 3;
      const _Float16* B0 = &Klds[qr << 8];
      const _Float16* B1 = &Klds[(16 + qr) << 8];
      const int bsz = (qr & 7) << 3;
      #pragma unroll
      for (int kk = 0; kk < 8; ++kk) {
        const int off = (kk << 5) + (kg << 3);
        half8 a  = *(const half8*)&Arow[off ^ asz];
        half8 b0 = *(const half8*)&B0[off ^ bsz];
        half8 b1 = *(const half8*)&B1[off ^ bsz];
        acc0 = __builtin_amdgcn_mfma_f32_16x16x32_f16(a, b0, acc0, 0, 0, 0);
        acc1 = __builtin_amdgcn_mfma_f32_16x16x32_f16(a, b1, acc1, 0, 0, 0);
      }
    }
    // ---- softmax over 32 keys per query row; P -> LDS (fp16) ----
    {
      const float b0v = kbias_s[qr], b1v = kbias_s[16 + qr];
      #pragma unroll
      for (int r = 0; r < 4; ++r) {
        float s0 = acc0[r] * 0.0625f + b0v;
        float s1 = acc1[r] * 0.0625f + b1v;
        float m = fmaxf(s0, s1);
        #pragma unroll
        for (int o = 1; o < 16; o <<= 1) m = fmaxf(m, __shfl_xor(m, o));
        float e0 = __expf(s0 - m), e1 = __expf(s1 - m);
        float sm = e0 + e1;
        #pragma unroll
        for (int o = 1; o < 16; o <<= 1) sm += __shfl_xor(sm, o);
        float inv = 1.0f / sm;
        int prow = (kg << 2) + r;
        _Float16* P = &Plds[(w << 9) + (prow << 5)];
        P[qr]      = (_Float16)(e0 * inv);
        P[16 + qr] = (_Float16)(e1 * inv);
      }
    }
    __builtin_amdgcn_wave_barrier();
    // ---- O = P K ; atomic accumulate ----
    {
      half8 a2 = *(const half8*)&Plds[(w << 9) + (qr << 5) + (kg << 3)];
      int nr[4];
      #pragma unroll
      for (int r = 0; r < 4; ++r) {
        int grow = (w << 4) + (kg << 2) + r;
        nr[r] = (grow < rmax) ? qlist[base + (chk << 6) + grow] : -1;
      }
      #pragma unroll
      for (int t = 0; t < 16; ++t) {
        half8 bb = *(const half8*)&KT[((t << 4) + qr) * 40 + (kg << 3)];
        f32x4 zero = {0.f, 0.f, 0.f, 0.f};
        f32x4 o = __builtin_amdgcn_mfma_f32_16x16x32_f16(a2, bb, zero, 0, 0, 0);
        #pragma unroll
        for (int r = 0; r < 4; ++r) {
          if (nr[r] >= 0)
            atomicAdd(&out[((size_t)((b << 12) + nr[r]) << 8) + (t << 4) + qr],
                      o[r] * (1.0f / 30.0f));
        }
      }
    }
  }
}

// ---------------------------------------------------------------------------
// workspace layout (bytes)
#define OFF_IDX   0                      // 128K
#define OFF_LOGW  131072                 // 128K
#define OFF_LBL   262144                 // 480K
#define OFF_NW    786432                 // 16 MB (ninvw table)
#define OFF_HIST  17563648               // 4K
#define OFF_BST   17567744               // 4K
#define OFF_CUR   17571840               // 4K
#define OFF_QL    17575936               // 1.875 MB (end ~19.5 MB)

extern "C" void kernel_launch(void* const* d_in, const int* in_sizes, int n_in,
                              void* d_out, int out_size, void* d_ws, size_t ws_size,
                              hipStream_t stream) {
  const float* x  = (const float*)d_in[0];
  const float* am = (const float*)d_in[1];
  float* out = (float*)d_out;

  char* ws = (char*)d_ws;
  int*   indices = (int*)(ws + OFF_IDX);
  float* logw    = (float*)(ws + OFF_LOGW);
  unsigned char* labels = (unsigned char*)(ws + OFF_LBL);
  float* ninvw   = (float*)(ws + OFF_NW);
  int*   hist    = (int*)(ws + OFF_HIST);
  int*   binstart= (int*)(ws + OFF_BST);
  int*   cursor  = (int*)(ws + OFF_CUR);
  int*   qlist   = (int*)(ws + OFF_QL);

  Keys30 keys;
  for (int s = 0; s < NSAMP; ++s) {
    unsigned o0, o1;
    threefry2x32(0u, 1u, 0u, (unsigned)s, o0, o1);
    keys.k0[s] = o0; keys.k1[s] = o1;
  }

  hipMemsetAsync(d_out, 0, (size_t)out_size * 4, stream);
  hipMemsetAsync(hist, 0, NBIN * 4, stream);

  invw_kernel<<<(BB * SS * NN) / (256 * 4), 256, 0, stream>>>(am, ninvw);
  topk_kernel<<<BB * SS, 256, 0, stream>>>(am, indices, logw);
  sample_ilp2_kernel<<<TOTQ / 64, 64, 0, stream>>>(ninvw, am, labels, keys);
  hist_kernel<<<240, 256, 0, stream>>>(labels, hist);
  scan_kernel<<<1, 1024, 0, stream>>>(hist, binstart, cursor);
  scatter_kernel<<<240, 256, 0, stream>>>(labels, cursor, qlist);
  attn_mfma_kernel<<<NBIN, 256, 0, stream>>>(x, indices, logw, qlist, binstart,
                                             hist, out);
}